// Round 1
// baseline (231.847 us; speedup 1.0000x reference)
//
#include <hip/hip_runtime.h>

// DynamicConvolution fused pipeline for MI355X (gfx950).
// Stages: K1 pooled/max-init -> K2 QKV gemm -> K3 ctrl params gemv ->
//         K4 flash attention + t_max -> K5 W_eff build -> K6 fused scene MLP.
// All heavy GEMMs use v_mfma_f32_16x16x32_bf16 with consistent A/B k-maps
// (k = 8*(lane>>4)+j) so results are k-permutation invariant; C/D layout is
// the HW-verified D[(lane>>4)*4+r][lane&15].

typedef __attribute__((ext_vector_type(8))) short short8;
typedef __attribute__((ext_vector_type(4))) float f32x4;

__device__ __forceinline__ unsigned short f2bf(float f){
  unsigned u = __float_as_uint(f);
  u += 0x7FFFu + ((u >> 16) & 1u);           // round-to-nearest-even
  return (unsigned short)(u >> 16);
}
// monotone float<->uint for atomicMax on floats (incl. negatives)
__device__ __forceinline__ unsigned fenc(float f){
  unsigned u = __float_as_uint(f);
  return (u & 0x80000000u) ? ~u : (u | 0x80000000u);
}
__device__ __forceinline__ float fdec(unsigned k){
  unsigned u = (k & 0x80000000u) ? (k & 0x7FFFFFFFu) : ~k;
  return __uint_as_float(u);
}

// ---------------- K1: pooled[b][c] = max_n T[b][c][n]; tmax_enc init -------------
__global__ __launch_bounds__(256) void k1_pooled(const float* __restrict__ T,
                                                 float* __restrict__ pooled,
                                                 unsigned* __restrict__ tmaxe){
  const int row = blockIdx.x;                 // b*256 + c
  const float* p = T + (size_t)row * 2048;
  const int tid = threadIdx.x;
  float m = -1e30f;
  for (int i = tid; i < 512; i += 256){
    float4 v = ((const float4*)p)[i];
    m = fmaxf(m, fmaxf(fmaxf(v.x, v.y), fmaxf(v.z, v.w)));
  }
  #pragma unroll
  for (int d = 1; d < 64; d <<= 1) m = fmaxf(m, __shfl_xor(m, d));
  __shared__ float sm[4];
  if ((tid & 63) == 0) sm[tid >> 6] = m;
  __syncthreads();
  if (tid == 0){
    pooled[row] = fmaxf(fmaxf(sm[0], sm[1]), fmaxf(sm[2], sm[3]));
    tmaxe[row] = 0u;                          // floor for encoded atomicMax
  }
}

// ---------------- K2: [q_w*0.125; k_w; v_w] (384x256) @ T[b] (256x2048) ----------
// outputs: Q[b][n][64] bf16 (prescaled), K[b][n][64] bf16, Vt[b][o][n] bf16
__global__ __launch_bounds__(256) void k2_qkv(const float* __restrict__ T,
    const float* __restrict__ qw, const float* __restrict__ kw,
    const float* __restrict__ vw,
    unsigned short* __restrict__ qo, unsigned short* __restrict__ ko,
    unsigned short* __restrict__ vt){
  const int b = blockIdx.z, mt = blockIdx.y, nt = blockIdx.x;
  const int m0 = mt * 128, n0 = nt * 128;
  __shared__ unsigned short As[128 * 40];     // [m][c], stride 40 (pad vs banks)
  __shared__ unsigned short Bs[128 * 40];     // [n][c] transposed from T
  const int tid = threadIdx.x;
  const int lane = tid & 63, w = tid >> 6;
  const int wr = w >> 1, wc = w & 1;
  const int l15 = lane & 15, g = lane >> 4;
  const float* Tb = T + (size_t)b * 256 * 2048;

  f32x4 acc[4][4];
  #pragma unroll
  for (int mi = 0; mi < 4; mi++)
    #pragma unroll
    for (int ni = 0; ni < 4; ni++) acc[mi][ni] = (f32x4){0.f,0.f,0.f,0.f};

  for (int k0 = 0; k0 < 256; k0 += 32){
    for (int e = tid; e < 4096; e += 256){    // A: W_all rows m0..+127, cols k0..+31
      int r = e >> 5, c = e & 31;
      int gm = m0 + r, gc = k0 + c;
      float v;
      if (gm < 64)       v = qw[gm * 256 + gc] * 0.125f;   // 1/sqrt(64) folded in
      else if (gm < 128) v = kw[(gm - 64) * 256 + gc];
      else               v = vw[(gm - 128) * 256 + gc];
      As[r * 40 + c] = f2bf(v);
    }
    for (int e = tid; e < 4096; e += 256){    // B: T[c][n] -> Bs[n][c]
      int cc = e >> 7, nn = e & 127;
      Bs[nn * 40 + cc] = f2bf(Tb[(size_t)(k0 + cc) * 2048 + n0 + nn]);
    }
    __syncthreads();
    short8 af[4], bfv[4];
    #pragma unroll
    for (int mi = 0; mi < 4; mi++)
      af[mi] = *(const short8*)&As[(wr * 64 + mi * 16 + l15) * 40 + g * 8];
    #pragma unroll
    for (int ni = 0; ni < 4; ni++)
      bfv[ni] = *(const short8*)&Bs[(wc * 64 + ni * 16 + l15) * 40 + g * 8];
    #pragma unroll
    for (int mi = 0; mi < 4; mi++)
      #pragma unroll
      for (int ni = 0; ni < 4; ni++)
        acc[mi][ni] = __builtin_amdgcn_mfma_f32_16x16x32_bf16(af[mi], bfv[ni], acc[mi][ni], 0, 0, 0);
    __syncthreads();
  }
  #pragma unroll
  for (int mi = 0; mi < 4; mi++)
    #pragma unroll
    for (int ni = 0; ni < 4; ni++)
      #pragma unroll
      for (int r = 0; r < 4; r++){
        int m = m0 + wr * 64 + mi * 16 + g * 4 + r;
        int n = n0 + wc * 64 + ni * 16 + l15;
        unsigned short v = f2bf(acc[mi][ni][r]);
        if (m < 64)       qo[((size_t)b * 2048 + n) * 64 + m] = v;
        else if (m < 128) ko[((size_t)b * 2048 + n) * 64 + (m - 64)] = v;
        else              vt[((size_t)b * 256 + (m - 128)) * 2048 + n] = v;
      }
}

// ---------------- K3: params[b][r] = pooled[b] . ctrl_w[r] + ctrl_b[r] -----------
__global__ __launch_bounds__(256) void k3_params(const float* __restrict__ pooled,
    const float* __restrict__ cw, const float* __restrict__ cb,
    float* __restrict__ params){
  __shared__ float P[8 * 256];
  const int tid = threadIdx.x;
  for (int i = tid; i < 2048; i += 256) P[i] = pooled[i];
  __syncthreads();
  const int w = tid >> 6, lane = tid & 63;
  const int r = blockIdx.x * 4 + w;
  if (r >= 8385) return;
  float4 c4 = ((const float4*)(cw + (size_t)r * 256))[lane];
  float bias = cb[r];
  #pragma unroll
  for (int b = 0; b < 8; b++){
    const float* pbp = P + b * 256 + lane * 4;
    float s = c4.x * pbp[0] + c4.y * pbp[1] + c4.z * pbp[2] + c4.w * pbp[3];
    #pragma unroll
    for (int d = 1; d < 64; d <<= 1) s += __shfl_xor(s, d);
    if (lane == 0) params[b * 8385 + r] = s + bias;
  }
}

// ---------------- K4: flash attention over template; t_max via atomicMax ---------
// 8 waves: QK^T split by m-cols (64 each, m-tile 512); PV split (h=n-half, q=o-quad)
__global__ __launch_bounds__(512) void k4_attn(const unsigned short* __restrict__ Qg,
    const unsigned short* __restrict__ Kg, const unsigned short* __restrict__ Vg,
    unsigned* __restrict__ tmaxe){
  const int b = blockIdx.y, rb = blockIdx.x;
  const int n0 = rb * 64;
  const int tid = threadIdx.x;
  const int lane = tid & 63, w = tid >> 6;
  const int l15 = lane & 15, g = lane >> 4;
  const int h = w >> 2, qq = w & 3;

  __shared__ unsigned short Pl[64 * 520];     // P tile bf16, stride 520 (16B pad)
  __shared__ float wstat[64 * 8];             // [row][wave]
  __shared__ float rstat[64];

  const unsigned short* Qb = Qg + (size_t)b * 2048 * 64;
  const unsigned short* Kb = Kg + (size_t)b * 2048 * 64;
  const unsigned short* Vb = Vg + (size_t)b * 256 * 2048;

  short8 qf[4][2];
  #pragma unroll
  for (int mi = 0; mi < 4; mi++)
    #pragma unroll
    for (int ks = 0; ks < 2; ks++)
      qf[mi][ks] = *(const short8*)(Qb + (size_t)(n0 + mi * 16 + l15) * 64 + ks * 32 + g * 8);

  float m_run[4][4], s_run[4][4];
  #pragma unroll
  for (int mi = 0; mi < 4; mi++)
    #pragma unroll
    for (int r = 0; r < 4; r++){ m_run[mi][r] = -1e30f; s_run[mi][r] = 0.f; }
  f32x4 y[2][4];
  #pragma unroll
  for (int yi = 0; yi < 2; yi++)
    #pragma unroll
    for (int ni = 0; ni < 4; ni++) y[yi][ni] = (f32x4){0.f,0.f,0.f,0.f};

  for (int it = 0; it < 4; ++it){
    const int mbase = it * 512;
    f32x4 sa[4][4];
    #pragma unroll
    for (int mi = 0; mi < 4; mi++)
      #pragma unroll
      for (int ni = 0; ni < 4; ni++) sa[mi][ni] = (f32x4){0.f,0.f,0.f,0.f};
    #pragma unroll
    for (int ni = 0; ni < 4; ni++)
      #pragma unroll
      for (int ks = 0; ks < 2; ks++){
        short8 kf = *(const short8*)(Kb + (size_t)(mbase + w * 64 + ni * 16 + l15) * 64 + ks * 32 + g * 8);
        #pragma unroll
        for (int mi = 0; mi < 4; mi++)
          sa[mi][ni] = __builtin_amdgcn_mfma_f32_16x16x32_bf16(qf[mi][ks], kf, sa[mi][ni], 0, 0, 0);
      }
    // per-wave row max over its 64 cols
    float wm[4][4];
    #pragma unroll
    for (int mi = 0; mi < 4; mi++)
      #pragma unroll
      for (int r = 0; r < 4; r++){
        float v = fmaxf(fmaxf(sa[mi][0][r], sa[mi][1][r]), fmaxf(sa[mi][2][r], sa[mi][3][r]));
        #pragma unroll
        for (int d = 1; d < 16; d <<= 1) v = fmaxf(v, __shfl_xor(v, d));
        wm[mi][r] = v;
      }
    if (l15 == 0){
      #pragma unroll
      for (int mi = 0; mi < 4; mi++)
        #pragma unroll
        for (int r = 0; r < 4; r++) wstat[(mi * 16 + g * 4 + r) * 8 + w] = wm[mi][r];
    }
    __syncthreads();
    if (tid < 64){
      float t = wstat[tid * 8];
      #pragma unroll
      for (int i = 1; i < 8; i++) t = fmaxf(t, wstat[tid * 8 + i]);
      rstat[tid] = t;
    }
    __syncthreads();
    float scl[4][4];
    #pragma unroll
    for (int mi = 0; mi < 4; mi++)
      #pragma unroll
      for (int r = 0; r < 4; r++){
        int row = mi * 16 + g * 4 + r;
        float mn = fmaxf(m_run[mi][r], rstat[row]);
        scl[mi][r] = __expf(m_run[mi][r] - mn);
        m_run[mi][r] = mn;
      }
    float ts[4][4];
    #pragma unroll
    for (int mi = 0; mi < 4; mi++)
      #pragma unroll
      for (int r = 0; r < 4; r++) ts[mi][r] = 0.f;
    #pragma unroll
    for (int mi = 0; mi < 4; mi++)
      #pragma unroll
      for (int ni = 0; ni < 4; ni++)
        #pragma unroll
        for (int r = 0; r < 4; r++){
          float p = __expf(sa[mi][ni][r] - m_run[mi][r]);
          Pl[(mi * 16 + g * 4 + r) * 520 + w * 64 + ni * 16 + l15] = f2bf(p);
          ts[mi][r] += p;
        }
    #pragma unroll
    for (int mi = 0; mi < 4; mi++)
      #pragma unroll
      for (int r = 0; r < 4; r++){
        float t = ts[mi][r];
        #pragma unroll
        for (int d = 1; d < 16; d <<= 1) t += __shfl_xor(t, d);
        s_run[mi][r] = s_run[mi][r] * scl[mi][r] + t;
      }
    // rescale running PV accumulator (rows of this wave: mi' = 2h+yi)
    #pragma unroll
    for (int yi = 0; yi < 2; yi++)
      #pragma unroll
      for (int ni = 0; ni < 4; ni++)
        #pragma unroll
        for (int r = 0; r < 4; r++) y[yi][ni][r] *= scl[2 * h + yi][r];
    __syncthreads();                          // P fully written
    for (int ks = 0; ks < 16; ks++){
      short8 pa[2];
      #pragma unroll
      for (int yi = 0; yi < 2; yi++)
        pa[yi] = *(const short8*)&Pl[(h * 32 + yi * 16 + l15) * 520 + ks * 32 + g * 8];
      #pragma unroll
      for (int ni = 0; ni < 4; ni++){
        short8 vf = *(const short8*)(Vb + (size_t)(qq * 64 + ni * 16 + l15) * 2048 + mbase + ks * 32 + g * 8);
        #pragma unroll
        for (int yi = 0; yi < 2; yi++)
          y[yi][ni] = __builtin_amdgcn_mfma_f32_16x16x32_bf16(pa[yi], vf, y[yi][ni], 0, 0, 0);
      }
    }
    __syncthreads();                          // PV reads done before next P write
  }
  // combine per-wave softmax denominators
  if (l15 == 0){
    #pragma unroll
    for (int mi = 0; mi < 4; mi++)
      #pragma unroll
      for (int r = 0; r < 4; r++) wstat[(mi * 16 + g * 4 + r) * 8 + w] = s_run[mi][r];
  }
  __syncthreads();
  if (tid < 64){
    float t = 0.f;
    #pragma unroll
    for (int i = 0; i < 8; i++) t += wstat[tid * 8 + i];
    rstat[tid] = t;
  }
  __syncthreads();
  float inv[2][4];
  #pragma unroll
  for (int yi = 0; yi < 2; yi++)
    #pragma unroll
    for (int r = 0; r < 4; r++) inv[yi][r] = 1.0f / rstat[h * 32 + yi * 16 + g * 4 + r];
  #pragma unroll
  for (int ni = 0; ni < 4; ni++){
    float cm = -1e30f;
    #pragma unroll
    for (int yi = 0; yi < 2; yi++)
      #pragma unroll
      for (int r = 0; r < 4; r++) cm = fmaxf(cm, y[yi][ni][r] * inv[yi][r]);
    cm = fmaxf(cm, __shfl_xor(cm, 16));
    cm = fmaxf(cm, __shfl_xor(cm, 32));
    if (lane < 16)
      atomicMax(&tmaxe[b * 256 + qq * 64 + ni * 16 + l15], fenc(cm));
  }
}

// ---------------- K5: W_eff = P0 + P1*t + P2 (bf16); bias_eff; w0/w1 -> bf16 -----
__global__ __launch_bounds__(256) void k5_weff(const float* __restrict__ proj_w,
    const float* __restrict__ proj_b, const unsigned* __restrict__ tmaxe,
    const float* __restrict__ params, unsigned short* __restrict__ weff,
    float* __restrict__ beff, unsigned short* __restrict__ w0b,
    unsigned short* __restrict__ w1b){
  const int b = blockIdx.y, o = blockIdx.x;
  const int c = threadIdx.x;                  // 256
  float t = fdec(tmaxe[b * 256 + c]);
  float p0 = proj_w[o * 768 + c];
  float p1 = proj_w[o * 768 + 256 + c];
  float p2 = proj_w[o * 768 + 512 + c];
  weff[((size_t)b * 64 + o) * 256 + c] = f2bf(p0 + p1 * t + p2);
  float s = p0 * t;
  #pragma unroll
  for (int d = 1; d < 64; d <<= 1) s += __shfl_xor(s, d);
  __shared__ float sm[4];
  if ((c & 63) == 0) sm[c >> 6] = s;
  __syncthreads();
  if (c == 0) beff[b * 64 + o] = proj_b[o] - (sm[0] + sm[1] + sm[2] + sm[3]);
  if (c < 64)        w0b[((size_t)b * 64 + o) * 64 + c] = f2bf(params[b * 8385 + o * 64 + c]);
  else if (c < 128)  w1b[((size_t)b * 64 + o) * 64 + (c - 64)] = f2bf(params[b * 8385 + 4096 + o * 64 + (c - 64)]);
}

// ---------------- K6: fused scene pipeline (scene read exactly once) -------------
__global__ __launch_bounds__(512) void k6_main(const float* __restrict__ Sg,
    const unsigned short* __restrict__ weff, const float* __restrict__ beff,
    const unsigned short* __restrict__ w0b, const unsigned short* __restrict__ w1b,
    const float* __restrict__ params, float* __restrict__ out){
  const int b = blockIdx.y, nt = blockIdx.x;
  const int n0 = nt * 256;
  const int tid = threadIdx.x, lane = tid & 63, w = tid >> 6;
  const int l15 = lane & 15, g = lane >> 4;
  __shared__ __align__(16) unsigned char smem[65536];
  unsigned short* H0 = (unsigned short*)smem;            // [n][64] XOR-swizzled, 32 KB
  unsigned short* U  = (unsigned short*)(smem + 32768);  // Bs then H1, 32 KB
  unsigned short* Bs = U;                                // [n][40]

  const float* Sb = Sg + (size_t)b * 256 * 16384;
  const unsigned short* We = weff + (size_t)b * 64 * 256;
  f32x4 a0[4][2];
  #pragma unroll
  for (int mi = 0; mi < 4; mi++)
    #pragma unroll
    for (int ni = 0; ni < 2; ni++) a0[mi][ni] = (f32x4){0.f,0.f,0.f,0.f};

  const int scc = tid >> 4;                   // 0..31 (c row within tile)
  const int snb = (tid & 15) * 16;            // n chunk base
  for (int k0 = 0; k0 < 256; k0 += 32){
    const float* src = Sb + (size_t)(k0 + scc) * 16384 + n0 + snb;
    float4 v0 = ((const float4*)src)[0];
    float4 v1 = ((const float4*)src)[1];
    float4 v2 = ((const float4*)src)[2];
    float4 v3 = ((const float4*)src)[3];
    float vals[16] = {v0.x,v0.y,v0.z,v0.w, v1.x,v1.y,v1.z,v1.w,
                      v2.x,v2.y,v2.z,v2.w, v3.x,v3.y,v3.z,v3.w};
    #pragma unroll
    for (int j = 0; j < 16; j++) Bs[(snb + j) * 40 + scc] = f2bf(vals[j]);
    __syncthreads();
    short8 bf0[2];
    #pragma unroll
    for (int ni = 0; ni < 2; ni++)
      bf0[ni] = *(const short8*)&Bs[(w * 32 + ni * 16 + l15) * 40 + g * 8];
    #pragma unroll
    for (int mi = 0; mi < 4; mi++){
      short8 af = *(const short8*)(We + (mi * 16 + l15) * 256 + k0 + g * 8);
      #pragma unroll
      for (int ni = 0; ni < 2; ni++)
        a0[mi][ni] = __builtin_amdgcn_mfma_f32_16x16x32_bf16(af, bf0[ni], a0[mi][ni], 0, 0, 0);
    }
    __syncthreads();
  }
  // layer0 epilogue: relu(+bias_eff) -> H0 [n][i] bf16, XOR swizzle on bits 4..6
  const float* be = beff + b * 64;
  #pragma unroll
  for (int mi = 0; mi < 4; mi++)
    #pragma unroll
    for (int ni = 0; ni < 2; ni++){
      int n = w * 32 + ni * 16 + l15;
      unsigned base = ((unsigned)(n * 128 + mi * 32 + g * 8)) ^ ((unsigned)((n & 7) << 4));
      unsigned short hh[4];
      #pragma unroll
      for (int r = 0; r < 4; r++){
        int o = mi * 16 + g * 4 + r;
        hh[r] = f2bf(fmaxf(a0[mi][ni][r] + be[o], 0.f));
      }
      *(unsigned*)((unsigned char*)H0 + base)     = (unsigned)hh[0] | ((unsigned)hh[1] << 16);
      *(unsigned*)((unsigned char*)H0 + base + 4) = (unsigned)hh[2] | ((unsigned)hh[3] << 16);
    }
  __syncthreads();
  // layer1: w0 @ h0
  f32x4 a1[4][2];
  #pragma unroll
  for (int mi = 0; mi < 4; mi++)
    #pragma unroll
    for (int ni = 0; ni < 2; ni++) a1[mi][ni] = (f32x4){0.f,0.f,0.f,0.f};
  const unsigned short* W0 = w0b + (size_t)b * 4096;
  #pragma unroll
  for (int ks = 0; ks < 2; ks++){
    short8 bfh[2];
    #pragma unroll
    for (int ni = 0; ni < 2; ni++){
      int n = w * 32 + ni * 16 + l15;
      unsigned off = ((unsigned)(n * 128 + ks * 64 + g * 16)) ^ ((unsigned)((n & 7) << 4));
      bfh[ni] = *(const short8*)((unsigned char*)H0 + off);
    }
    #pragma unroll
    for (int mi = 0; mi < 4; mi++){
      short8 af = *(const short8*)(W0 + (mi * 16 + l15) * 64 + ks * 32 + g * 8);
      #pragma unroll
      for (int ni = 0; ni < 2; ni++)
        a1[mi][ni] = __builtin_amdgcn_mfma_f32_16x16x32_bf16(af, bfh[ni], a1[mi][ni], 0, 0, 0);
    }
  }
  const float* pp = params + (size_t)b * 8385;
  const float* b0p = pp + 8256;
  unsigned short* H1 = U;                     // Bs dead after layer0
  #pragma unroll
  for (int mi = 0; mi < 4; mi++)
    #pragma unroll
    for (int ni = 0; ni < 2; ni++){
      int n = w * 32 + ni * 16 + l15;
      unsigned base = ((unsigned)(n * 128 + mi * 32 + g * 8)) ^ ((unsigned)((n & 7) << 4));
      unsigned short hh[4];
      #pragma unroll
      for (int r = 0; r < 4; r++){
        int o = mi * 16 + g * 4 + r;
        hh[r] = f2bf(fmaxf(a1[mi][ni][r] + b0p[o], 0.f));
      }
      *(unsigned*)((unsigned char*)H1 + base)     = (unsigned)hh[0] | ((unsigned)hh[1] << 16);
      *(unsigned*)((unsigned char*)H1 + base + 4) = (unsigned)hh[2] | ((unsigned)hh[3] << 16);
    }
  __syncthreads();
  // layer2: w1 @ h1, then fused w2 dot + b2
  f32x4 a2[4][2];
  #pragma unroll
  for (int mi = 0; mi < 4; mi++)
    #pragma unroll
    for (int ni = 0; ni < 2; ni++) a2[mi][ni] = (f32x4){0.f,0.f,0.f,0.f};
  const unsigned short* W1 = w1b + (size_t)b * 4096;
  #pragma unroll
  for (int ks = 0; ks < 2; ks++){
    short8 bfh[2];
    #pragma unroll
    for (int ni = 0; ni < 2; ni++){
      int n = w * 32 + ni * 16 + l15;
      unsigned off = ((unsigned)(n * 128 + ks * 64 + g * 16)) ^ ((unsigned)((n & 7) << 4));
      bfh[ni] = *(const short8*)((unsigned char*)H1 + off);
    }
    #pragma unroll
    for (int mi = 0; mi < 4; mi++){
      short8 af = *(const short8*)(W1 + (mi * 16 + l15) * 64 + ks * 32 + g * 8);
      #pragma unroll
      for (int ni = 0; ni < 2; ni++)
        a2[mi][ni] = __builtin_amdgcn_mfma_f32_16x16x32_bf16(af, bfh[ni], a2[mi][ni], 0, 0, 0);
    }
  }
  const float* b1p = pp + 8320;
  const float* w2p = pp + 8192;
  float b2v = pp[8384];
  #pragma unroll
  for (int ni = 0; ni < 2; ni++){
    float t = 0.f;
    #pragma unroll
    for (int mi = 0; mi < 4; mi++)
      #pragma unroll
      for (int r = 0; r < 4; r++){
        int o = mi * 16 + g * 4 + r;
        t += w2p[o] * fmaxf(a2[mi][ni][r] + b1p[o], 0.f);
      }
    t += __shfl_xor(t, 16);
    t += __shfl_xor(t, 32);
    if (lane < 16)
      out[(size_t)b * 16384 + n0 + w * 32 + ni * 16 + l15] = t + b2v;
  }
}

extern "C" void kernel_launch(void* const* d_in, const int* in_sizes, int n_in,
                              void* d_out, int out_size, void* d_ws, size_t ws_size,
                              hipStream_t stream){
  const float* scene = (const float*)d_in[0];
  const float* tmpl  = (const float*)d_in[1];
  const float* qw    = (const float*)d_in[2];
  const float* kw    = (const float*)d_in[3];
  const float* vw    = (const float*)d_in[4];
  const float* pw    = (const float*)d_in[5];
  const float* pb    = (const float*)d_in[6];
  const float* cw    = (const float*)d_in[7];
  const float* cb    = (const float*)d_in[8];
  float* out = (float*)d_out;
  char* ws = (char*)d_ws;

  unsigned short* Q    = (unsigned short*)(ws + 0);                    // 2 MB
  unsigned short* K    = (unsigned short*)(ws + (2u << 20));           // 2 MB
  unsigned short* V    = (unsigned short*)(ws + (4u << 20));           // 8 MB
  float*          pooled = (float*)(ws + (12u << 20));                 // 8 KB
  unsigned*       tmaxe  = (unsigned*)(ws + (12u << 20) + 8192);       // 8 KB
  float*          params = (float*)(ws + (12u << 20) + 16384);         // 268 KB
  unsigned short* w0b  = (unsigned short*)(ws + (13u << 20));          // 64 KB
  unsigned short* w1b  = (unsigned short*)(ws + (13u << 20) + 65536);  // 64 KB
  unsigned short* weff = (unsigned short*)(ws + (13u << 20) + 131072); // 256 KB
  float*          beff = (float*)(ws + (13u << 20) + 131072 + 262144); // 2 KB

  k1_pooled<<<dim3(2048), dim3(256), 0, stream>>>(tmpl, pooled, tmaxe);
  k2_qkv<<<dim3(16, 3, 8), dim3(256), 0, stream>>>(tmpl, qw, kw, vw, Q, K, V);
  k3_params<<<dim3(2097), dim3(256), 0, stream>>>(pooled, cw, cb, params);
  k4_attn<<<dim3(32, 8), dim3(512), 0, stream>>>(Q, K, V, tmaxe);
  k5_weff<<<dim3(64, 8), dim3(256), 0, stream>>>(pw, pb, tmaxe, params, weff, beff, w0b, w1b);
  k6_main<<<dim3(64, 8), dim3(512), 0, stream>>>(scene, weff, beff, w0b, w1b, params, out);
}